// Round 1
// baseline (368.272 us; speedup 1.0000x reference)
//
#include <hip/hip_runtime.h>

// Problem constants (fixed by setup_inputs): B=256, N=512.
constexpr int B = 256;
constexpr int NELEM = 512 * 512;          // elements per batch
constexpr int BLOCKS_PER_B = 8;           // partial-sum blocks per batch
constexpr int THREADS = 256;
constexpr int F4_PER_BLOCK = NELEM / 4 / BLOCKS_PER_B;   // 8192 float4 per block
constexpr int F4_PER_THREAD = F4_PER_BLOCK / THREADS;    // 32
constexpr float MARGIN = 0.5f;
constexpr int NUM_PAIRS = B * (B - 1) / 2;               // 32640

// Stage 1: per-(batch, chunk) partial sums. Pure streaming reduction,
// float4 coalesced: lane i reads consecutive 16B — 1 KiB / wave / instr.
__global__ void __launch_bounds__(THREADS) gsim_partial_kernel(
    const float* __restrict__ graph, float* __restrict__ partials) {
    const int b   = blockIdx.x / BLOCKS_PER_B;
    const int blk = blockIdx.x % BLOCKS_PER_B;
    const float4* src = reinterpret_cast<const float4*>(
                            graph + (size_t)b * NELEM)
                        + (size_t)blk * F4_PER_BLOCK;

    float sum = 0.0f;
#pragma unroll
    for (int it = 0; it < F4_PER_THREAD; ++it) {
        float4 v = src[it * THREADS + threadIdx.x];
        sum += (v.x + v.y) + (v.z + v.w);
    }

    // wave (64-lane) shuffle reduce
#pragma unroll
    for (int off = 32; off > 0; off >>= 1)
        sum += __shfl_down(sum, off, 64);

    __shared__ float wsum[THREADS / 64];
    const int lane = threadIdx.x & 63;
    const int wid  = threadIdx.x >> 6;
    if (lane == 0) wsum[wid] = sum;
    __syncthreads();
    if (threadIdx.x == 0)
        partials[blockIdx.x] = (wsum[0] + wsum[1]) + (wsum[2] + wsum[3]);
}

// Stage 2: one block. Finish means, compute pairwise hinge loss over the
// upper triangle, reduce, normalize.
__global__ void __launch_bounds__(THREADS) finalize_kernel(
    const float* __restrict__ partials, const int* __restrict__ labels,
    float* __restrict__ out) {
    __shared__ float gs[B];
    __shared__ int   lab[B];
    const int t = threadIdx.x;

    float s = 0.0f;
#pragma unroll
    for (int k = 0; k < BLOCKS_PER_B; ++k)
        s += partials[t * BLOCKS_PER_B + k];
    gs[t]  = s * (1.0f / (float)NELEM);
    lab[t] = labels[t];
    __syncthreads();

    const float gi = gs[t];
    const int   li = lab[t];
    float acc = 0.0f;
    for (int j = t + 1; j < B; ++j) {
        const float sim = gi * gs[j];
        const float pl  = (li == lab[j]) ? fmaxf(MARGIN - sim, 0.0f)
                                         : fmaxf(sim - (1.0f - MARGIN), 0.0f);
        acc += pl;
    }

#pragma unroll
    for (int off = 32; off > 0; off >>= 1)
        acc += __shfl_down(acc, off, 64);

    __shared__ float wsum[THREADS / 64];
    if ((t & 63) == 0) wsum[t >> 6] = acc;
    __syncthreads();
    if (t == 0)
        out[0] = ((wsum[0] + wsum[1]) + (wsum[2] + wsum[3]))
                 * (1.0f / (float)NUM_PAIRS);
}

extern "C" void kernel_launch(void* const* d_in, const int* in_sizes, int n_in,
                              void* d_out, int out_size, void* d_ws, size_t ws_size,
                              hipStream_t stream) {
    const float* graph  = (const float*)d_in[0];   // [B, 512, 512] fp32
    const int*   labels = (const int*)d_in[1];     // [B] int
    float* out = (float*)d_out;                    // scalar fp32
    float* partials = (float*)d_ws;                // B * BLOCKS_PER_B floats

    gsim_partial_kernel<<<B * BLOCKS_PER_B, THREADS, 0, stream>>>(graph, partials);
    finalize_kernel<<<1, THREADS, 0, stream>>>(partials, labels, out);
}